// Round 3
// baseline (577.008 us; speedup 1.0000x reference)
//
#include <hip/hip_runtime.h>
#include <hip/hip_bf16.h>
#include <math.h>

// Problem constants (S, B, D_IN, D_SRC, D_ALIGN = 2048, 64, 512, 512, 512)
#define S_LEN 2048
#define BATCH 64
#define DDIM 512

typedef __attribute__((ext_vector_type(8))) short bf16x8;
typedef __attribute__((ext_vector_type(4))) float f32x4;
typedef __attribute__((ext_vector_type(4))) unsigned int u32x4;

typedef __attribute__((address_space(1))) const void g_void;
typedef __attribute__((address_space(3))) void l_void;

#define ROT8(n) ((((n) ^ ((n) >> 3))) & 7)

__device__ __forceinline__ unsigned short f2bf(float f) {
  unsigned int u = __float_as_uint(f);
  u += 0x7fffu + ((u >> 16) & 1u);
  return (unsigned short)(u >> 16);
}

__device__ __forceinline__ float tanh_fast(float x) {
  // tanh(x) = 1 - 2/(exp2(2*log2e*x)+1)
  float e = __builtin_amdgcn_exp2f(x * 2.88539008177793f);
  return 1.0f - 2.0f * __builtin_amdgcn_rcpf(e + 1.0f);
}

// ---------------------------------------------------------------------------
// prep: W1b[a][d] = bf16(W1[a][512+d]);  uprime[b][a] = b1[a] + W1[a,:512].input[b]
// ---------------------------------------------------------------------------
__global__ __launch_bounds__(256) void prep_kernel(
    const float* __restrict__ W1, const float* __restrict__ b1,
    const float* __restrict__ input, unsigned short* __restrict__ W1b,
    float* __restrict__ uprime) {
  __shared__ float w1row[1024];
  const int a = blockIdx.x;
  const int t = threadIdx.x;
  float4 v = *(const float4*)(W1 + a * 1024 + t * 4);
  *(float4*)(w1row + t * 4) = v;
  if (t >= 128) {
    ushort4 u;
    u.x = f2bf(v.x); u.y = f2bf(v.y); u.z = f2bf(v.z); u.w = f2bf(v.w);
    *(ushort4*)(W1b + a * 512 + (t * 4 - 512)) = u;
  }
  __syncthreads();
  if (t < BATCH) {
    const float4* inp = (const float4*)(input + t * 512);
    const float4* wr = (const float4*)w1row;
    float acc = b1[a];
#pragma unroll 4
    for (int d = 0; d < 128; ++d) {
      float4 x = inp[d], w = wr[d];
      acc += x.x * w.x + x.y * w.y + x.z * w.z + x.w * w.w;
    }
    uprime[t * 512 + a] = acc;  // [b][a]
  }
}

// ---------------------------------------------------------------------------
// scores v3: GEMM M=131072 (s*64+b), N=512, K=512. Block tile 128x128, BK=64.
// grid = 1024 M-tiles x 4 N-tiles (N-tiles adjacent in blockIdx for L3 reuse
// of the A-tile). 256 thr / 4 waves; wave (mw,nw) owns 64x64 -> acc 4x4.
// A: fp32 src staged manually -> bf16 LDS, row stride 72 us (144 B: octet
//    addresses r*144+ks*64+q*16 mod 128 all distinct -> conflict-free b128).
// B: global_load_lds w/ XOR chunk swizzle chunk_phys = chunk_log ^ ROT8(n)
//    (row stride 128 B; swizzle spreads octets -> conflict-free b128).
// Epilogue: tanh + W2 partial dot, LDS-reduce, global atomicAdd partial
// scores (scores pre-zeroed; b2 omitted -- constant shift cancels in softmax).
// ---------------------------------------------------------------------------
#define ASTR 72  // A_lds row stride in ushorts

__global__ __launch_bounds__(256, 3) void scores_kernel(
    const float* __restrict__ src, const unsigned short* __restrict__ W1b,
    const float* __restrict__ uprime, const float* __restrict__ W2,
    float* __restrict__ scores_g) {
  __shared__ unsigned short A_sm[128 * ASTR];  // 18 KB
  __shared__ unsigned short B_sm[128 * 64];    // 16 KB
  __shared__ float s_lds[128];

  const int t = threadIdx.x;
  const int m0 = blockIdx.x >> 2;        // M-tile
  const int n0 = (blockIdx.x & 3) << 7;  // N-tile base col
  const int w = t >> 6;                  // wave 0..3
  const int lane = t & 63;
  const int quad = lane >> 4;
  const int l15 = lane & 15;
  const int mw = w & 1, nw = w >> 1;

  if (t < 128) s_lds[t] = 0.f;

  f32x4 acc[4][4];
#pragma unroll
  for (int i = 0; i < 4; ++i)
#pragma unroll
    for (int j = 0; j < 4; ++j) acc[i][j] = (f32x4){0.f, 0.f, 0.f, 0.f};

  // ---- A staging addresses: thread t covers row arow, 32-k half ahalf ----
  const int arow = t >> 1;
  const int ahalf = t & 1;
  const float* gA = src + (size_t)(m0 * 128 + arow) * DDIM + ahalf * 32;
  unsigned short* ldsA = A_sm + arow * ASTR + ahalf * 32;

  // ---- B staging: 4 global_load_lds per wave, 8 rows each ----
  const int brow = lane >> 3;   // 0..7 within group
  const int bchunk = lane & 7;  // phys 16B chunk
  const unsigned short* gB[4];
  unsigned short* ldsB[4];
#pragma unroll
  for (int g = 0; g < 4; ++g) {
    const int nl = w * 32 + g * 8 + brow;
    gB[g] = W1b + (size_t)(n0 + nl) * DDIM + ((bchunk ^ ROT8(nl)) << 3);
    ldsB[g] = B_sm + (w * 32 + g * 8) * 64;  // wave-uniform base
  }

  for (int k0 = 0; k0 < DDIM; k0 += 64) {
    // ---- stage B (async) ----
#pragma unroll
    for (int g = 0; g < 4; ++g)
      __builtin_amdgcn_global_load_lds((g_void*)gB[g], (l_void*)ldsB[g], 16, 0, 0);
    // ---- stage A: 8 float4 -> 32 bf16 -> 4 ds_write_b128 ----
    float4 v[8];
#pragma unroll
    for (int f = 0; f < 8; ++f) v[f] = ((const float4*)gA)[f];
#pragma unroll
    for (int f = 0; f < 4; ++f) {
      unsigned x0 = __float_as_uint(v[2 * f].x) + 0x8000u;
      unsigned y0 = __float_as_uint(v[2 * f].y) + 0x8000u;
      unsigned z0 = __float_as_uint(v[2 * f].z) + 0x8000u;
      unsigned w0 = __float_as_uint(v[2 * f].w) + 0x8000u;
      unsigned x1 = __float_as_uint(v[2 * f + 1].x) + 0x8000u;
      unsigned y1 = __float_as_uint(v[2 * f + 1].y) + 0x8000u;
      unsigned z1 = __float_as_uint(v[2 * f + 1].z) + 0x8000u;
      unsigned w1 = __float_as_uint(v[2 * f + 1].w) + 0x8000u;
      u32x4 o;
      o.x = __builtin_amdgcn_perm(y0, x0, 0x07060302u);
      o.y = __builtin_amdgcn_perm(w0, z0, 0x07060302u);
      o.z = __builtin_amdgcn_perm(y1, x1, 0x07060302u);
      o.w = __builtin_amdgcn_perm(w1, z1, 0x07060302u);
      *(u32x4*)(ldsA + f * 8) = o;
    }
    gA += 64;
#pragma unroll
    for (int g = 0; g < 4; ++g) gB[g] += 64;
    __syncthreads();

    // ---- compute: 2 k-chunks x (8 ds_read_b128 + 16 MFMA) ----
#pragma unroll
    for (int ks = 0; ks < 2; ++ks) {
      bf16x8 af[4], bfr[4];
#pragma unroll
      for (int i = 0; i < 4; ++i)
        af[i] = *(const bf16x8*)(A_sm + (mw * 64 + i * 16 + l15) * ASTR + ks * 32 + quad * 8);
#pragma unroll
      for (int j = 0; j < 4; ++j) {
        const int nl = nw * 64 + j * 16 + l15;
        af[0] = af[0];  // no-op
        bfr[j] = *(const bf16x8*)(B_sm + nl * 64 + (((ks * 4 + quad) ^ ROT8(nl)) << 3));
      }
#pragma unroll
      for (int i = 0; i < 4; ++i)
#pragma unroll
        for (int j = 0; j < 4; ++j)
          acc[i][j] = __builtin_amdgcn_mfma_f32_16x16x32_bf16(af[i], bfr[j], acc[i][j], 0, 0, 0);
    }
    __syncthreads();
  }

  // ---- epilogue ----
  float w2r[4];
#pragma unroll
  for (int j = 0; j < 4; ++j) w2r[j] = W2[n0 + nw * 64 + j * 16 + l15];

#pragma unroll
  for (int i = 0; i < 4; ++i) {
#pragma unroll
    for (int r = 0; r < 4; ++r) {
      const int rloc = mw * 64 + i * 16 + quad * 4 + r;  // D row
      const int b = rloc & 63;                            // batch (m0*128 % 64 == 0)
      const float* up = uprime + b * 512 + n0 + nw * 64 + l15;
      float sp = 0.f;
#pragma unroll
      for (int j = 0; j < 4; ++j)
        sp += w2r[j] * tanh_fast(acc[i][j][r] + up[j * 16]);
      sp += __shfl_xor(sp, 1);
      sp += __shfl_xor(sp, 2);
      sp += __shfl_xor(sp, 4);
      sp += __shfl_xor(sp, 8);
      if (l15 == 0) atomicAdd(&s_lds[rloc], sp);
    }
  }
  __syncthreads();
  if (t < 128) atomicAdd(scores_g + m0 * 128 + t, s_lds[t]);
}

// ---------------------------------------------------------------------------
// softmax over s for each b (mask applied here; b2 omitted -- cancels).
// ---------------------------------------------------------------------------
__global__ __launch_bounds__(256) void softmax_kernel(
    const float* __restrict__ scores_g, const unsigned char* __restrict__ mask,
    float* __restrict__ attn_g) {
  __shared__ float red[256];
  const int b = blockIdx.x, t = threadIdx.x;
  float m = -__builtin_inff();
  float sc[8];
#pragma unroll
  for (int c = 0; c < 8; ++c) {
    const int s = t + c * 256;
    sc[c] = mask[s * BATCH + b] ? -__builtin_inff() : scores_g[s * BATCH + b];
    m = fmaxf(m, sc[c]);
  }
  red[t] = m;
  __syncthreads();
  for (int off = 128; off; off >>= 1) {
    if (t < off) red[t] = fmaxf(red[t], red[t + off]);
    __syncthreads();
  }
  m = red[0];
  __syncthreads();
  float sum = 0.f;
#pragma unroll
  for (int c = 0; c < 8; ++c) sum += __expf(sc[c] - m);
  red[t] = sum;
  __syncthreads();
  for (int off = 128; off; off >>= 1) {
    if (t < off) red[t] += red[t + off];
    __syncthreads();
  }
  const float inv = 1.f / red[0];
#pragma unroll
  for (int c = 0; c < 8; ++c)
    attn_g[(t + c * 256) * BATCH + b] = __expf(sc[c] - m) * inv;
}

// ---------------------------------------------------------------------------
// ctx[b][d] = sum_s attn[s][b] * src[s][b][d]. grid (16 s-chunks, 64 b),
// float4 loads, atomicAdd into zeroed ctx.
// ---------------------------------------------------------------------------
__global__ __launch_bounds__(256) void ctx_kernel(
    const float* __restrict__ src, const float* __restrict__ attn_g,
    float* __restrict__ ctx) {
  __shared__ float a_lds[128];
  const int s0 = blockIdx.x * 128, b = blockIdx.y, t = threadIdx.x;
  if (t < 128) a_lds[t] = attn_g[(s0 + t) * BATCH + b];
  __syncthreads();
  const int f4i = t & 127;     // float4 index within the 512-d row
  const int sh = t >> 7;       // s-half (64 each)
  const float4* base = (const float4*)src + ((size_t)(s0 + sh * 64) * BATCH + b) * 128 + f4i;
  float4 acc = {0.f, 0.f, 0.f, 0.f};
#pragma unroll 8
  for (int i = 0; i < 64; ++i) {
    const float a = a_lds[sh * 64 + i];
    float4 v = base[(size_t)i * BATCH * 128];
    acc.x += a * v.x; acc.y += a * v.y; acc.z += a * v.z; acc.w += a * v.w;
  }
  float* cp = ctx + b * DDIM + f4i * 4;
  atomicAdd(cp + 0, acc.x);
  atomicAdd(cp + 1, acc.y);
  atomicAdd(cp + 2, acc.z);
  atomicAdd(cp + 3, acc.w);
}

// ---------------------------------------------------------------------------
extern "C" void kernel_launch(void* const* d_in, const int* in_sizes, int n_in,
                              void* d_out, int out_size, void* d_ws, size_t ws_size,
                              hipStream_t stream) {
  const float* input = (const float*)d_in[0];
  const float* src = (const float*)d_in[1];
  const unsigned char* mask = (const unsigned char*)d_in[2];
  const float* W1 = (const float*)d_in[3];
  const float* b1 = (const float*)d_in[4];
  const float* W2 = (const float*)d_in[5];
  // d_in[6] = b2: omitted (constant shift cancels in softmax)

  float* ctx = (float*)d_out;                  // [64,512]
  float* attn = (float*)d_out + BATCH * DDIM;  // [2048,64]

  unsigned short* W1b = (unsigned short*)d_ws;                      // 512 KB
  float* uprime = (float*)((char*)d_ws + 512 * 1024);               // 128 KB
  float* scores = (float*)((char*)d_ws + 512 * 1024 + 128 * 1024);  // 512 KB

  hipMemsetAsync(ctx, 0, BATCH * DDIM * sizeof(float), stream);
  hipMemsetAsync(scores, 0, S_LEN * BATCH * sizeof(float), stream);
  prep_kernel<<<512, 256, 0, stream>>>(W1, b1, input, W1b, uprime);
  scores_kernel<<<4096, 256, 0, stream>>>(src, W1b, uprime, W2, scores);
  softmax_kernel<<<BATCH, 256, 0, stream>>>(scores, mask, attn);
  ctx_kernel<<<dim3(16, BATCH), 256, 0, stream>>>(src, attn, ctx);
}

// Round 4
// 493.771 us; speedup vs baseline: 1.1686x; 1.1686x over previous
//
#include <hip/hip_runtime.h>
#include <hip/hip_bf16.h>
#include <math.h>

// Problem constants (S, B, D_IN, D_SRC, D_ALIGN = 2048, 64, 512, 512, 512)
#define S_LEN 2048
#define BATCH 64
#define DDIM 512

typedef __attribute__((ext_vector_type(8))) short bf16x8;
typedef __attribute__((ext_vector_type(4))) float f32x4;
typedef __attribute__((ext_vector_type(4))) unsigned int u32x4;

typedef __attribute__((address_space(1))) const void g_void;
typedef __attribute__((address_space(3))) void l_void;

__device__ __forceinline__ unsigned short f2bf(float f) {
  unsigned int u = __float_as_uint(f);
  u += 0x7fffu + ((u >> 16) & 1u);
  return (unsigned short)(u >> 16);
}

__device__ __forceinline__ float tanh_fast(float x) {
  // tanh(x) = 1 - 2/(exp2(2*log2e*x)+1)
  float e = __builtin_amdgcn_exp2f(x * 2.88539008177793f);
  return 1.0f - 2.0f * __builtin_amdgcn_rcpf(e + 1.0f);
}

// ---------------------------------------------------------------------------
// prep: W1b[a][d] = bf16(W1[a][512+d]);  uprime[b][a] = b1[a] + W1[a,:512].input[b]
// ---------------------------------------------------------------------------
__global__ __launch_bounds__(256) void prep_kernel(
    const float* __restrict__ W1, const float* __restrict__ b1,
    const float* __restrict__ input, unsigned short* __restrict__ W1b,
    float* __restrict__ uprime) {
  __shared__ float w1row[1024];
  const int a = blockIdx.x;
  const int t = threadIdx.x;
  float4 v = *(const float4*)(W1 + a * 1024 + t * 4);
  *(float4*)(w1row + t * 4) = v;
  if (t >= 128) {
    ushort4 u;
    u.x = f2bf(v.x); u.y = f2bf(v.y); u.z = f2bf(v.z); u.w = f2bf(v.w);
    *(ushort4*)(W1b + a * 512 + (t * 4 - 512)) = u;
  }
  __syncthreads();
  if (t < BATCH) {
    const float4* inp = (const float4*)(input + t * 512);
    const float4* wr = (const float4*)w1row;
    float acc = b1[a];
#pragma unroll 4
    for (int d = 0; d < 128; ++d) {
      float4 x = inp[d], w = wr[d];
      acc += x.x * w.x + x.y * w.y + x.z * w.z + x.w * w.w;
    }
    uprime[t * 512 + a] = acc;  // [b][a]
  }
}

// ---------------------------------------------------------------------------
// scores v4: block per s (A read ONCE, FETCH ~139 MB). 512 thr / 8 waves,
// BK=64 (8 iters, 32 MFMA/wave per barrier). Wave w owns cols w*64..w*64+63.
// LDS: A 64x64 bf16 (8 KB), B 512x64 bf16 (64 KB) -> 72 KB, 2 blocks/CU.
// XOR-chunk swizzle on both (phys 16B-chunk p holds logical c = p ^ (row&7))
// -> every ds op is <=2-way conflict (free, m136). B via global_load_lds x8.
// Epilogue: tanh + W2 dot, LDS reduce, write scores_t[b][s] (transposed!).
// b2 omitted (constant shift cancels in softmax).
// ---------------------------------------------------------------------------
__global__ __launch_bounds__(512, 4) void scores_kernel(
    const float* __restrict__ src, const unsigned short* __restrict__ W1b,
    const float* __restrict__ uprime, const float* __restrict__ W2,
    float* __restrict__ scores_t) {
  __shared__ unsigned short A_sm[64 * 64];   // 8 KB
  __shared__ unsigned short B_sm[512 * 64];  // 64 KB
  __shared__ float s_lds[BATCH];

  const int t = threadIdx.x;
  const int s = blockIdx.x;
  const int w = t >> 6;        // wave 0..7 (uniform)
  const int lane = t & 63;
  const int quad = lane >> 4;
  const int l15 = lane & 15;

  if (t < BATCH) s_lds[t] = 0.f;

  f32x4 acc[4][4];
#pragma unroll
  for (int i = 0; i < 4; ++i)
#pragma unroll
    for (int j = 0; j < 4; ++j) acc[i][j] = (f32x4){0.f, 0.f, 0.f, 0.f};

  const float* srcblk = src + (size_t)s * (BATCH * DDIM);
  // A staging: thread t -> row ar=t>>3, phys chunk ap=t&7, logical ac=ap^(ar&7)
  const int ar = t >> 3, ap = t & 7, ac = ap ^ (ar & 7);
  const float* gA = srcblk + ar * DDIM + ac * 8;
  unsigned short* ldsA = A_sm + ar * 64 + ap * 8;
  // B staging lane-invariant part: row-in-group br=lane>>3, phys bp=lane&7
  const int br = lane >> 3, bp = lane & 7, bc = bp ^ (br & 7);
  const unsigned short* gBl = W1b + br * DDIM + bc * 8;

  for (int k0 = 0; k0 < DDIM; k0 += 64) {
    // ---- stage B: 8 async GLL per wave (rows g*64+w*8 .. +7) ----
#pragma unroll
    for (int g = 0; g < 8; ++g) {
      const unsigned short* gp = gBl + (g * 64 + w * 8) * DDIM + k0;
      unsigned short* lp = B_sm + (g * 64 + w * 8) * 64;  // wave-uniform
      __builtin_amdgcn_global_load_lds((g_void*)gp, (l_void*)lp, 16, 0, 0);
    }
    // ---- stage A: 8 fp32 -> 8 bf16 -> one ds_write_b128 ----
    {
      const float4 v0 = *(const float4*)(gA + k0);
      const float4 v1 = *(const float4*)(gA + k0 + 4);
      unsigned x0 = __float_as_uint(v0.x) + 0x8000u;
      unsigned y0 = __float_as_uint(v0.y) + 0x8000u;
      unsigned z0 = __float_as_uint(v0.z) + 0x8000u;
      unsigned w0 = __float_as_uint(v0.w) + 0x8000u;
      unsigned x1 = __float_as_uint(v1.x) + 0x8000u;
      unsigned y1 = __float_as_uint(v1.y) + 0x8000u;
      unsigned z1 = __float_as_uint(v1.z) + 0x8000u;
      unsigned w1 = __float_as_uint(v1.w) + 0x8000u;
      u32x4 o;
      o.x = __builtin_amdgcn_perm(y0, x0, 0x07060302u);
      o.y = __builtin_amdgcn_perm(w0, z0, 0x07060302u);
      o.z = __builtin_amdgcn_perm(y1, x1, 0x07060302u);
      o.w = __builtin_amdgcn_perm(w1, z1, 0x07060302u);
      *(u32x4*)ldsA = o;
    }
    __syncthreads();

    // ---- compute: 2 k-chunks x (8 ds_read_b128 + 16 MFMA) per wave ----
#pragma unroll
    for (int ks = 0; ks < 2; ++ks) {
      const int c = ks * 4 + quad;  // logical 16B chunk within BK=64
      bf16x8 af[4], bfr[4];
#pragma unroll
      for (int i = 0; i < 4; ++i) {
        const int r = i * 16 + l15;
        af[i] = *(const bf16x8*)(A_sm + r * 64 + ((c ^ (r & 7)) << 3));
      }
#pragma unroll
      for (int j = 0; j < 4; ++j) {
        const int n = w * 64 + j * 16 + l15;
        bfr[j] = *(const bf16x8*)(B_sm + n * 64 + ((c ^ (n & 7)) << 3));
      }
#pragma unroll
      for (int i = 0; i < 4; ++i)
#pragma unroll
        for (int j = 0; j < 4; ++j)
          acc[i][j] = __builtin_amdgcn_mfma_f32_16x16x32_bf16(af[i], bfr[j], acc[i][j], 0, 0, 0);
    }
    __syncthreads();
  }

  // ---- epilogue: tanh + W2 partial dot over this wave's 64 cols ----
  float w2r[4];
#pragma unroll
  for (int j = 0; j < 4; ++j) w2r[j] = W2[w * 64 + j * 16 + l15];

#pragma unroll
  for (int i = 0; i < 4; ++i) {
#pragma unroll
    for (int r = 0; r < 4; ++r) {
      const int b = i * 16 + quad * 4 + r;  // D row = local batch
      const float* up = uprime + b * 512 + w * 64 + l15;
      float sp = 0.f;
#pragma unroll
      for (int j = 0; j < 4; ++j)
        sp += w2r[j] * tanh_fast(acc[i][j][r] + up[j * 16]);
      sp += __shfl_xor(sp, 1);
      sp += __shfl_xor(sp, 2);
      sp += __shfl_xor(sp, 4);
      sp += __shfl_xor(sp, 8);
      if (l15 == 0) atomicAdd(&s_lds[b], sp);
    }
  }
  __syncthreads();
  if (t < BATCH) scores_t[t * S_LEN + s] = s_lds[t];  // transposed [b][s]
}

// ---------------------------------------------------------------------------
// softmax over s per b; reads contiguous scores_t[b][s]. Writes attn[s][b]
// (output) and optionally attn_t[b][s] (ws, contiguous for ctx).
// ---------------------------------------------------------------------------
__global__ __launch_bounds__(256) void softmax_kernel(
    const float* __restrict__ scores_t, const unsigned char* __restrict__ mask,
    float* __restrict__ attn_g, float* __restrict__ attn_t, int write_t) {
  __shared__ float red[256];
  const int b = blockIdx.x, t = threadIdx.x;
  float m = -__builtin_inff();
  float sc[8];
#pragma unroll
  for (int c = 0; c < 8; ++c) {
    const int s = t + c * 256;
    sc[c] = mask[s * BATCH + b] ? -__builtin_inff() : scores_t[b * S_LEN + s];
    m = fmaxf(m, sc[c]);
  }
  red[t] = m;
  __syncthreads();
  for (int off = 128; off; off >>= 1) {
    if (t < off) red[t] = fmaxf(red[t], red[t + off]);
    __syncthreads();
  }
  m = red[0];
  __syncthreads();
  float sum = 0.f;
#pragma unroll
  for (int c = 0; c < 8; ++c) sum += __expf(sc[c] - m);
  red[t] = sum;
  __syncthreads();
  for (int off = 128; off; off >>= 1) {
    if (t < off) red[t] += red[t + off];
    __syncthreads();
  }
  const float inv = 1.f / red[0];
#pragma unroll
  for (int c = 0; c < 8; ++c) {
    const int s = t + c * 256;
    const float p = __expf(sc[c] - m) * inv;
    attn_g[s * BATCH + b] = p;
    if (write_t) attn_t[b * S_LEN + s] = p;
  }
}

// ---------------------------------------------------------------------------
// ctx two-stage (no atomics). Stage 1: grid (32 s-chunks, 64 b), each block
// computes two 32-s half-partials (float4 stores, coalesced).
// ---------------------------------------------------------------------------
__global__ __launch_bounds__(256) void ctx_partial_kernel(
    const float* __restrict__ src, const float* __restrict__ attn_t,
    float* __restrict__ partial) {
  __shared__ float a_lds[64];
  const int c = blockIdx.x;  // 0..31
  const int b = blockIdx.y;  // 0..63
  const int t = threadIdx.x;
  if (t < 64) a_lds[t] = attn_t[b * S_LEN + c * 64 + t];
  __syncthreads();
  const int f4i = t & 127;
  const int sh = t >> 7;
  const float4* base =
      (const float4*)src + ((size_t)(c * 64 + sh * 32) * BATCH + b) * 128 + f4i;
  float4 acc = {0.f, 0.f, 0.f, 0.f};
#pragma unroll 8
  for (int i = 0; i < 32; ++i) {
    const float a = a_lds[sh * 32 + i];
    float4 v = base[(size_t)i * BATCH * 128];
    acc.x += a * v.x; acc.y += a * v.y; acc.z += a * v.z; acc.w += a * v.w;
  }
  ((float4*)partial)[((size_t)(c * 2 + sh) * BATCH + b) * 128 + f4i] = acc;
}

// Stage 2: ctx[b][d] = sum over 64 half-partials. grid 64, 256 thr (float2/thr).
__global__ __launch_bounds__(256) void ctx_reduce_kernel(
    const float* __restrict__ partial, float* __restrict__ ctx) {
  const int b = blockIdx.x, t = threadIdx.x;
  const float2* p = (const float2*)partial + (size_t)b * 256 + t;
  float2 acc = {0.f, 0.f};
#pragma unroll 8
  for (int c2 = 0; c2 < 64; ++c2) {
    float2 v = p[(size_t)c2 * BATCH * 256];
    acc.x += v.x; acc.y += v.y;
  }
  ((float2*)ctx)[b * 256 + t] = acc;
}

// Fallback ctx (small ws): atomicAdd into zeroed ctx, reads attn [s][b].
__global__ __launch_bounds__(256) void ctx_atomic_kernel(
    const float* __restrict__ src, const float* __restrict__ attn_g,
    float* __restrict__ ctx) {
  __shared__ float a_lds[128];
  const int s0 = blockIdx.x * 128, b = blockIdx.y, t = threadIdx.x;
  if (t < 128) a_lds[t] = attn_g[(s0 + t) * BATCH + b];
  __syncthreads();
  const int f4i = t & 127;
  const int sh = t >> 7;
  const float4* base =
      (const float4*)src + ((size_t)(s0 + sh * 64) * BATCH + b) * 128 + f4i;
  float4 acc = {0.f, 0.f, 0.f, 0.f};
#pragma unroll 8
  for (int i = 0; i < 64; ++i) {
    const float a = a_lds[sh * 64 + i];
    float4 v = base[(size_t)i * BATCH * 128];
    acc.x += a * v.x; acc.y += a * v.y; acc.z += a * v.z; acc.w += a * v.w;
  }
  float* cp = ctx + b * DDIM + f4i * 4;
  atomicAdd(cp + 0, acc.x);
  atomicAdd(cp + 1, acc.y);
  atomicAdd(cp + 2, acc.z);
  atomicAdd(cp + 3, acc.w);
}

// ---------------------------------------------------------------------------
extern "C" void kernel_launch(void* const* d_in, const int* in_sizes, int n_in,
                              void* d_out, int out_size, void* d_ws, size_t ws_size,
                              hipStream_t stream) {
  const float* input = (const float*)d_in[0];
  const float* src = (const float*)d_in[1];
  const unsigned char* mask = (const unsigned char*)d_in[2];
  const float* W1 = (const float*)d_in[3];
  const float* b1 = (const float*)d_in[4];
  const float* W2 = (const float*)d_in[5];
  // d_in[6] = b2: omitted (constant shift cancels in softmax)

  float* ctx = (float*)d_out;                  // [64,512]
  float* attn = (float*)d_out + BATCH * DDIM;  // [2048,64]

  // ws layout
  unsigned short* W1b = (unsigned short*)d_ws;                        // 512 KB
  float* uprime = (float*)((char*)d_ws + 512 * 1024);                 // 128 KB
  float* scores_t = (float*)((char*)d_ws + 640 * 1024);               // 512 KB
  float* attn_t = (float*)((char*)d_ws + 1152 * 1024);                // 512 KB
  float* partial = (float*)((char*)d_ws + 1664 * 1024);               // 8 MB
  const size_t NEED_ATTN_T = 1664 * 1024;
  const size_t NEED_PARTIAL = 1664 * 1024 + (size_t)64 * BATCH * DDIM * 4;
  const int have_attn_t = ws_size >= NEED_ATTN_T;
  const int have_partial = ws_size >= NEED_PARTIAL;

  prep_kernel<<<512, 256, 0, stream>>>(W1, b1, input, W1b, uprime);
  scores_kernel<<<S_LEN, 512, 0, stream>>>(src, W1b, uprime, W2, scores_t);
  softmax_kernel<<<BATCH, 256, 0, stream>>>(scores_t, mask, attn, attn_t,
                                            have_attn_t && have_partial);
  if (have_partial) {
    ctx_partial_kernel<<<dim3(32, BATCH), 256, 0, stream>>>(src, attn_t, partial);
    ctx_reduce_kernel<<<BATCH, 256, 0, stream>>>(partial, ctx);
  } else {
    hipMemsetAsync(ctx, 0, BATCH * DDIM * sizeof(float), stream);
    ctx_atomic_kernel<<<dim3(16, BATCH), 256, 0, stream>>>(src, attn, ctx);
  }
}